// Round 10
// baseline (143.039 us; speedup 1.0000x reference)
//
#include <hip/hip_runtime.h>

typedef float f32x16 __attribute__((ext_vector_type(16)));
typedef float f32x2 __attribute__((ext_vector_type(2)));
typedef short short8 __attribute__((ext_vector_type(8)));
typedef unsigned short u16;
typedef unsigned int u32;

#define SEQ_L 2048

#if __has_builtin(__builtin_amdgcn_exp2f)
#define EXP2(x) __builtin_amdgcn_exp2f(x)
#else
#define EXP2(x) exp2f(x)
#endif

__device__ __forceinline__ u32 pk2bf(float lo, float hi) {
#if __has_builtin(__builtin_amdgcn_cvt_pk_bf16_f32)
    typedef __bf16 bf16x2_t __attribute__((ext_vector_type(2)));
    union { bf16x2_t v; u32 i; } w;
    w.v = __builtin_amdgcn_cvt_pk_bf16_f32(lo, hi);
    return w.i;
#else
    union { float f; u32 i; } a, b; a.f = lo; b.f = hi;
    return ((a.i + 0x8000u) >> 16) | ((b.i + 0x8000u) & 0xFFFF0000u);
#endif
}

// kt: XOR-swizzled [s][c] bf16, 128 rows x stride 64 u16; 16B chunk l of row
// s at l ^ (((s>>2)^s)&7) — sw depends only on low bits so rows s and s+64
// share patterns. vt: s-permuted [c][s'] bf16, stride 136 u16 (272B rows,
// 16B-aligned); within each 16-group of s the order [0-3,8-11,4-7,12-15]
// makes each A-fragment one contiguous 16B chunk.
#define KT_U16 (128 * 64)             // 8192
#define VT_STRIDE 136
#define VT_U16 (64 * VT_STRIDE)       // 8704
#define GRP_U16 (KT_U16 + VT_U16)     // 16896 u16 per s-group
#define SMEM_U16 (2 * GRP_U16)        // 33792 u16 = 67584 B (== epilogue need)

// WG = 8 waves (512 thr): 2 s-groups x 4 t-waves x 64 t (two 32-t tiles).
// Grid 256 = 32 heads x 8 tb; ~1 WG/CU. BK=128: stage 128 s per barrier pair
// (8 iters), compute as two independent 64-s sub-tiles back-to-back — the
// per-iteration fixed cost (barriers, waitcnt drains, phase convoy ramp)
// halves per score, and the two sub-tiles' chains interleave without a
// barrier (sub-1 ds_reads fill sub-0's exp2/trans phase).
__global__ __launch_bounds__(512, 2)
void attn_kernel(const float* __restrict__ qkv, float* __restrict__ out) {
    const int tid  = threadIdx.x;
    const int lane = tid & 63;
    const int wv   = tid >> 6;        // 0..7
    const int g    = wv >> 2;         // s-group 0/1
    const int wvin = wv & 3;          // t-wave within group
    const int col  = lane & 31;
    const int half = lane >> 5;

    const int gid  = blockIdx.x;
    const int head = gid & 31;        // head h -> XCD h%8
    const int tb   = gid >> 5;        // 0..7
    const int t0   = tb * 256 + wvin * 64;
    const int bb   = head >> 3, hh = head & 7;

    const size_t qoff = ((size_t)bb * 1536 + (size_t)hh * 64) * SEQ_L;
    const float* qp = qkv + qoff;
    const float* kp = qp + (size_t)512  * SEQ_L;
    const float* vp = qp + (size_t)1024 * SEQ_L;
    float* op = out + ((size_t)bb * 512 + (size_t)hh * 64) * SEQ_L;

    __shared__ __align__(16) u16 smem[SMEM_U16];
    u16* ktg = smem + g * GRP_U16;
    u16* vtg = ktg + KT_U16;

    // Staging: 16-lane sets read 256B runs along s; each thread covers
    // s-chunk 4*sgrp and 64+4*sgrp (both halves of the 128-s tile).
    const int gtid = tid & 255;
    const int sgrp = gtid & 15;
    const int rq   = gtid >> 4;       // K rows 4rq..4rq+3 / V rows rq+16rr
    const int sbase0 = g * 1024;

    // ---- hoisted LDS write pointers ----
    u16* kw[4];                        // second half: kw[j] + 64*64
#pragma unroll
    for (int j = 0; j < 4; ++j) {
        int s = 4 * sgrp + j;
        int sw = ((s >> 2) ^ s) & 7;
        kw[j] = ktg + s * 64 + (((rq >> 1) ^ sw) << 3) + ((rq & 1) << 2);
    }
    const int vcoloff = ((sgrp >> 2) << 4) + ((sgrp & 1) << 3) + (((sgrp >> 1) & 1) << 2);
    u16* vw = vtg + rq * VT_STRIDE + vcoloff;   // second half: +64

    // ---- hoisted LDS read offsets ----
    const int sw_r = ((col >> 2) ^ col) & 7;    // same for all needed rows
    int kco[4];
#pragma unroll
    for (int ks = 0; ks < 4; ++ks) kco[ks] = ((2 * ks + half) ^ sw_r) << 3;
    const u16* krb[2][2];              // [sub][mb]
#pragma unroll
    for (int sub = 0; sub < 2; ++sub) {
        krb[sub][0] = ktg + (sub * 64 + col) * 64;
        krb[sub][1] = ktg + (sub * 64 + 32 + col) * 64;
    }
    const u16* vrb0 = vtg + col * VT_STRIDE + half * 8;
    const u16* vrb1 = vtg + (32 + col) * VT_STRIDE + half * 8;

    // ---- preload Q B-fragments for BOTH t-tiles (prescaled) ----
    const int tA = t0 + col;
    const int tB = tA + 32;
    const float qscale = 0.18033688f;  // (1/8)*log2(e)
    short8 qfA[4], qfB[4];
#pragma unroll
    for (int ks = 0; ks < 4; ++ks) {
        union { u32 u[4]; short8 v; } qa, qb;
#pragma unroll
        for (int e2 = 0; e2 < 4; ++e2) {
            int c = ks * 16 + half * 8 + 2 * e2;
            const float* c0 = qp + (size_t)c * SEQ_L;
            const float* c1 = qp + (size_t)(c + 1) * SEQ_L;
            qa.u[e2] = pk2bf(c0[tA] * qscale, c1[tA] * qscale);
            qb.u[e2] = pk2bf(c0[tB] * qscale, c1[tB] * qscale);
        }
        qfA[ks] = qa.v; qfB[ks] = qb.v;
    }

    f32x16 zacc;
#pragma unroll
    for (int r = 0; r < 16; ++r) zacc[r] = 0.0f;

    f32x16 accO[2][2];                 // [t-tile][mbc]
#pragma unroll
    for (int tt = 0; tt < 2; ++tt)
#pragma unroll
        for (int m = 0; m < 2; ++m)
#pragma unroll
            for (int r = 0; r < 16; ++r) accO[tt][m][r] = 0.0f;
    f32x2 lsA = {0.0f, 0.0f}, lsB = {0.0f, 0.0f};

    float4 kreg[8], vreg[8];           // [rr] first 64 s, [4+rr] second 64 s
    auto load_tile = [&](int sb) {
#pragma unroll
        for (int rr = 0; rr < 4; ++rr) {
            const float* kr = kp + (size_t)(4 * rq + rr) * SEQ_L + sb + 4 * sgrp;
            const float* vr = vp + (size_t)(rq + 16 * rr) * SEQ_L + sb + 4 * sgrp;
            kreg[rr]     = *(const float4*)(kr);
            kreg[4 + rr] = *(const float4*)(kr + 64);
            vreg[rr]     = *(const float4*)(vr);
            vreg[4 + rr] = *(const float4*)(vr + 64);
        }
    };
    auto publish = [&]() {
#pragma unroll
        for (int hs = 0; hs < 2; ++hs) {
#pragma unroll
            for (int j = 0; j < 4; ++j) {
                uint2 w;
                w.x = pk2bf(kreg[4 * hs + 0][j], kreg[4 * hs + 1][j]);
                w.y = pk2bf(kreg[4 * hs + 2][j], kreg[4 * hs + 3][j]);
                *(uint2*)(kw[j] + hs * 64 * 64) = w;
            }
#pragma unroll
            for (int rr = 0; rr < 4; ++rr) {
                uint2 w;
                w.x = pk2bf(vreg[4 * hs + rr].x, vreg[4 * hs + rr].y);
                w.y = pk2bf(vreg[4 * hs + rr].z, vreg[4 * hs + rr].w);
                *(uint2*)(vw + 16 * rr * VT_STRIDE + hs * 64) = w;
            }
        }
    };

    load_tile(sbase0);

    for (int it = 0; it < 8; ++it) {
        __syncthreads();   // previous tile fully consumed
        publish();
        __syncthreads();
        if (it + 1 < 8) load_tile(sbase0 + (it + 1) * 128);

        // ---- two independent 64-s sub-tiles (no barrier between) ----
#pragma unroll
        for (int sub = 0; sub < 2; ++sub) {
            // S^T = K^T * Q for both t-tiles
            f32x16 accA[2], accB[2];
#pragma unroll
            for (int mb = 0; mb < 2; ++mb) {
                const u16* rb = krb[sub][mb];
                short8 kf0 = *(const short8*)(rb + kco[0]);
                accA[mb] = __builtin_amdgcn_mfma_f32_32x32x16_bf16(kf0, qfA[0], zacc, 0, 0, 0);
                accB[mb] = __builtin_amdgcn_mfma_f32_32x32x16_bf16(kf0, qfB[0], zacc, 0, 0, 0);
#pragma unroll
                for (int ks = 1; ks < 4; ++ks) {
                    short8 kf = *(const short8*)(rb + kco[ks]);
                    accA[mb] = __builtin_amdgcn_mfma_f32_32x32x16_bf16(kf, qfA[ks], accA[mb], 0, 0, 0);
                    accB[mb] = __builtin_amdgcn_mfma_f32_32x32x16_bf16(kf, qfB[ks], accB[mb], 0, 0, 0);
                }
            }

            // exp2 + packed sums + bf16 pack
            u32 pregA[2][8], pregB[2][8];
#pragma unroll
            for (int mb = 0; mb < 2; ++mb) {
                f32x2 a2[4], b2[4];
#pragma unroll
                for (int u2 = 0; u2 < 8; ++u2) {
                    float ax = EXP2(accA[mb][2 * u2]);
                    float ay = EXP2(accA[mb][2 * u2 + 1]);
                    pregA[mb][u2] = pk2bf(ax, ay);
                    f32x2 av = {ax, ay};
                    if (u2 < 4) a2[u2] = av; else a2[u2 - 4] += av;
                }
                lsA += (a2[0] + a2[1]) + (a2[2] + a2[3]);
#pragma unroll
                for (int u2 = 0; u2 < 8; ++u2) {
                    float bx = EXP2(accB[mb][2 * u2]);
                    float by = EXP2(accB[mb][2 * u2 + 1]);
                    pregB[mb][u2] = pk2bf(bx, by);
                    f32x2 bv = {bx, by};
                    if (u2 < 4) b2[u2] = bv; else b2[u2 - 4] += bv;
                }
                lsB += (b2[0] + b2[1]) + (b2[2] + b2[3]);
            }

            // O += V * P^T for both t-tiles
#pragma unroll
            for (int mk = 0; mk < 4; ++mk) {
                int mb = mk >> 1, kb = mk & 1;
                union { u32 u[4]; short8 v; } bfA, bfB;
#pragma unroll
                for (int i = 0; i < 4; ++i) {
                    bfA.u[i] = pregA[mb][4 * kb + i];
                    bfB.u[i] = pregB[mb][4 * kb + i];
                }
#pragma unroll
                for (int mbc = 0; mbc < 2; ++mbc) {
                    short8 vf = *(const short8*)((mbc ? vrb1 : vrb0) + sub * 64 + mk * 16);
                    accO[0][mbc] = __builtin_amdgcn_mfma_f32_32x32x16_bf16(vf, bfA.v, accO[0][mbc], 0, 0, 0);
                    accO[1][mbc] = __builtin_amdgcn_mfma_f32_32x32x16_bf16(vf, bfB.v, accO[1][mbc], 0, 0, 0);
                }
            }
        }
    }

    float lsum[2];
    lsum[0] = lsA[0] + lsA[1];
    lsum[1] = lsB[0] + lsB[1];

    // ---- combine the two s-groups (linear), then store ----
    __syncthreads();                    // staging LDS dead; reuse for exchange
    float* ep = (float*)smem;           // [(wvin*64+lane)*2+tt][33], 67584 B
    if (g == 1) {
#pragma unroll
        for (int tt = 0; tt < 2; ++tt) {
            float* row = ep + ((wvin * 64 + lane) * 2 + tt) * 33;
#pragma unroll
            for (int mbc = 0; mbc < 2; ++mbc)
#pragma unroll
                for (int r = 0; r < 16; ++r) row[mbc * 16 + r] = accO[tt][mbc][r];
            row[32] = lsum[tt];
        }
    }
    __syncthreads();
    if (g == 0) {
#pragma unroll
        for (int tt = 0; tt < 2; ++tt) {
            const float* row = ep + ((wvin * 64 + lane) * 2 + tt) * 33;
#pragma unroll
            for (int mbc = 0; mbc < 2; ++mbc)
#pragma unroll
                for (int r = 0; r < 16; ++r) accO[tt][mbc][r] += row[mbc * 16 + r];
            float lt = lsum[tt] + row[32];
            float ltot = lt + __shfl_xor(lt, 32, 64);
            float inv = 1.0f / ltot;
            const int t = tt ? tB : tA;
#pragma unroll
            for (int mbc = 0; mbc < 2; ++mbc) {
#pragma unroll
                for (int r = 0; r < 16; ++r) {
                    int c = mbc * 32 + (r & 3) + 8 * (r >> 2) + 4 * half;
                    op[(size_t)c * SEQ_L + t] = accO[tt][mbc][r] * inv;
                }
            }
        }
    }
}

extern "C" void kernel_launch(void* const* d_in, const int* in_sizes, int n_in,
                              void* d_out, int out_size, void* d_ws, size_t ws_size,
                              hipStream_t stream) {
    (void)in_sizes; (void)n_in; (void)d_ws; (void)ws_size; (void)out_size;
    const float* qkv = (const float*)d_in[0];
    float* out = (float*)d_out;
    attn_kernel<<<dim3(256), dim3(512), 0, stream>>>(qkv, out);
}